// Round 9
// baseline (184.603 us; speedup 1.0000x reference)
//
#include <hip/hip_runtime.h>
#include <math.h>

#define NDIM 128

typedef __bf16 bf16x8 __attribute__((ext_vector_type(8)));
typedef float  f32x4  __attribute__((ext_vector_type(4)));

// f32 pair -> packed bf16x2 (round-to-nearest-even)
__device__ __forceinline__ unsigned pack_bf16x2(float a, float b) {
    unsigned ua = __float_as_uint(a), ub = __float_as_uint(b);
    ua = (ua + 0x7FFFu + ((ua >> 16) & 1u)) >> 16;
    ub = (ub + 0x7FFFu + ((ub >> 16) & 1u)) >> 16;
    return ua | (ub << 16);
}
__device__ __forceinline__ float bf_lo(unsigned p) { return __uint_as_float(p << 16); }
__device__ __forceinline__ float bf_hi(unsigned p) { return __uint_as_float(p & 0xFFFF0000u); }

// ---------------------------------------------------------------------------
// K0: prep. block 0: W[k][n] f32 -> Wt[n][k] bf16.  block 1: s2[] row dots.
// ---------------------------------------------------------------------------
__global__ __launch_bounds__(256) void k_prep(
    const float* __restrict__ W, const float* __restrict__ W_r,
    const float* __restrict__ a, const float* __restrict__ rel_emb,
    unsigned short* __restrict__ Wt, float* __restrict__ s2)
{
    if (blockIdx.x == 0) {
        for (int i = threadIdx.x; i < NDIM * NDIM; i += 256) {
            int n = i & 127, k = i >> 7;
            float v = W[k * NDIM + n];
            Wt[n * NDIM + k] = (unsigned short)(pack_bf16x2(v, 0.f) & 0xFFFFu);
        }
    } else {
        __shared__ float vsh[NDIM];
        const int t = threadIdx.x;
        if (t < 128) {
            float acc = 0.f;
            for (int c = 0; c < NDIM; ++c)
                acc = fmaf(W_r[t * NDIM + c], a[128 + c], acc);
            vsh[t] = acc;
        }
        __syncthreads();
        if (t < 64) {
            float s = 0.f;
            for (int k = 0; k < NDIM; ++k)
                s = fmaf(rel_emb[t * NDIM + k], vsh[k], s);
            s2[t] = s;
        }
    }
}

// ---------------------------------------------------------------------------
// K1: xt = x @ W via mfma_f32_16x16x32_bf16. 128 rows/block, 4 waves.
//     Single 32KB LDS buffer (W, swizzled; reused for output restage).
// ---------------------------------------------------------------------------
__global__ __launch_bounds__(256) void k_xt(
    const float* __restrict__ x, const unsigned short* __restrict__ Wt,
    const float* __restrict__ a,
    unsigned* __restrict__ xtb,   // N*64 uints (bf16x2)
    float* __restrict__ s1, float* __restrict__ s3,
    int n_nodes)
{
    __shared__ __align__(16) unsigned short WL[NDIM * NDIM]; // 32 KB
    const int tid  = threadIdx.x;
    const int lane = tid & 63;
    const int wave = tid >> 6;
    const int l15  = lane & 15;
    const int l4   = lane >> 4;
    char* wb = (char*)WL;

    for (int i = tid * 8; i < NDIM * NDIM; i += 256 * 8) {
        int nn = i >> 7, k = i & 127;
        uint4 v = *reinterpret_cast<const uint4*>(Wt + i);
        *reinterpret_cast<uint4*>(wb + ((nn * 256 + k * 2) ^ ((nn & 7) << 4))) = v;
    }
    __syncthreads();

    const int rowBase = blockIdx.x * 128;

    f32x4 acc[2][8];
    #pragma unroll
    for (int i = 0; i < 2; ++i)
        #pragma unroll
        for (int j = 0; j < 8; ++j) acc[i][j] = (f32x4){0.f, 0.f, 0.f, 0.f};

    #pragma unroll
    for (int kt = 0; kt < 4; ++kt) {
        const int kb2 = (kt * 32 + l4 * 8) * 2;
        bf16x8 af[2], bf[8];
        #pragma unroll
        for (int rf = 0; rf < 2; ++rf) {
            int r = rowBase + wave * 32 + rf * 16 + l15;
            float4 lo = make_float4(0.f, 0.f, 0.f, 0.f);
            float4 hi = lo;
            if (r < n_nodes) {
                const float* px = &x[(size_t)r * NDIM + kt * 32 + l4 * 8];
                lo = *reinterpret_cast<const float4*>(px);
                hi = *reinterpret_cast<const float4*>(px + 4);
            }
            uint4 u;
            u.x = pack_bf16x2(lo.x, lo.y);
            u.y = pack_bf16x2(lo.z, lo.w);
            u.z = pack_bf16x2(hi.x, hi.y);
            u.w = pack_bf16x2(hi.z, hi.w);
            af[rf] = __builtin_bit_cast(bf16x8, u);
        }
        #pragma unroll
        for (int cf = 0; cf < 8; ++cf) {
            int n = cf * 16 + l15;
            bf[cf] = *reinterpret_cast<bf16x8*>(wb + ((n * 256 + kb2) ^ ((n & 7) << 4)));
        }
        #pragma unroll
        for (int rf = 0; rf < 2; ++rf)
            #pragma unroll
            for (int cf = 0; cf < 8; ++cf)
                acc[rf][cf] = __builtin_amdgcn_mfma_f32_16x16x32_bf16(
                    af[rf], bf[cf], acc[rf][cf], 0, 0, 0);
    }

    // s1/s3: C/D layout col=lane&15, row=(lane>>4)*4+reg
    float av1[8], av3[8];
    #pragma unroll
    for (int cf = 0; cf < 8; ++cf) {
        av1[cf] = a[cf * 16 + l15];
        av3[cf] = a[256 + cf * 16 + l15];
    }
    #pragma unroll
    for (int rf = 0; rf < 2; ++rf) {
        #pragma unroll
        for (int reg = 0; reg < 4; ++reg) {
            float p1 = 0.f, p3 = 0.f;
            #pragma unroll
            for (int cf = 0; cf < 8; ++cf) {
                p1 = fmaf(acc[rf][cf][reg], av1[cf], p1);
                p3 = fmaf(acc[rf][cf][reg], av3[cf], p3);
            }
            #pragma unroll
            for (int off = 8; off; off >>= 1) {
                p1 += __shfl_xor(p1, off);
                p3 += __shfl_xor(p3, off);
            }
            if (l15 == 0) {
                int r = rowBase + wave * 32 + rf * 16 + l4 * 4 + reg;
                if (r < n_nodes) { s1[r] = p1; s3[r] = p3; }
            }
        }
    }

    __syncthreads();
    #pragma unroll
    for (int rf = 0; rf < 2; ++rf)
        #pragma unroll
        for (int cf = 0; cf < 8; ++cf)
            #pragma unroll
            for (int reg = 0; reg < 4; ++reg) {
                int r = wave * 32 + rf * 16 + l4 * 4 + reg;
                int c = cf * 16 + l15;
                *reinterpret_cast<unsigned short*>(wb + ((r * 256 + c * 2) ^ ((r & 7) << 4))) =
                    (unsigned short)(pack_bf16x2(acc[rf][cf][reg], 0.f) & 0xFFFFu);
            }
    __syncthreads();
    for (int i = tid * 8; i < NDIM * NDIM; i += 256 * 8) {
        int r = i >> 7, k = i & 127;
        if (rowBase + r < n_nodes) {
            uint4 v = *reinterpret_cast<uint4*>(wb + ((r * 256 + k * 2) ^ ((r & 7) << 4)));
            *reinterpret_cast<uint4*>(&xtb[(size_t)(rowBase + r) * 64 + (k >> 1)]) = v;
        }
    }
}

// ---------------------------------------------------------------------------
// K3: in-degree histogram, 4 edges/thread (int4 load, plain int4 store)
// ---------------------------------------------------------------------------
__global__ __launch_bounds__(256) void k_count(
    const int* __restrict__ dst, int* __restrict__ deg,
    int* __restrict__ eord, int n_edges)
{
    int e = (blockIdx.x * 256 + threadIdx.x) * 4;
    if (e + 3 < n_edges) {
        int4 d = *reinterpret_cast<const int4*>(&dst[e]);
        int4 o;
        o.x = atomicAdd(&deg[d.x], 1);
        o.y = atomicAdd(&deg[d.y], 1);
        o.z = atomicAdd(&deg[d.z], 1);
        o.w = atomicAdd(&deg[d.w], 1);
        *reinterpret_cast<int4*>(&eord[e]) = o;
    } else {
        for (int k = 0; k < 4 && e + k < n_edges; ++k)
            eord[e + k] = atomicAdd(&deg[dst[e + k]], 1);
    }
}

// ---------------------------------------------------------------------------
// K4a: block scan via wave shuffles; packs {prefix:20, deg:12} into one word
// ---------------------------------------------------------------------------
__global__ __launch_bounds__(1024) void k_scan1(
    const int* __restrict__ deg, int* __restrict__ packed,
    int* __restrict__ btot, int n)
{
    __shared__ int wt[16];
    const int tid = threadIdx.x;
    const int lane = tid & 63;
    const int wv = tid >> 6;
    const int i = blockIdx.x * 1024 + tid;
    int v = (i < n) ? deg[i] : 0;
    int s = v;
    #pragma unroll
    for (int off = 1; off < 64; off <<= 1) {
        int t = __shfl_up(s, off);
        if (lane >= off) s += t;
    }
    if (lane == 63) wt[wv] = s;
    __syncthreads();
    if (wv == 0) {
        int x = (lane < 16) ? wt[lane] : 0;
        #pragma unroll
        for (int off = 1; off < 16; off <<= 1) {
            int t = __shfl_up(x, off);
            if (lane >= off) x += t;
        }
        if (lane < 16) wt[lane] = x;
        if (lane == 15) btot[blockIdx.x] = x;
    }
    __syncthreads();
    int base = (wv == 0) ? 0 : wt[wv - 1];
    if (i < n)
        packed[i] = (int)(((unsigned)(base + s - v) << 12) | (unsigned)v);
}

// K4b: exclusive scan of block totals (one block; nb <= 128)
__global__ __launch_bounds__(128) void k_scan2(int* __restrict__ bt, int nb)
{
    __shared__ int sh[128];
    const int t = threadIdx.x;
    int v = (t < nb) ? bt[t] : 0;
    sh[t] = v;
    __syncthreads();
    for (int off = 1; off < 128; off <<= 1) {
        int x = sh[t];
        if (t >= off) x += sh[t - off];
        __syncthreads();
        sh[t] = x;
        __syncthreads();
    }
    if (t < nb) bt[t] = sh[t] - v;
}

// ---------------------------------------------------------------------------
// K5: att weight + CSR placement, 4 edges/thread: all 12 random gathers
//     (s1/s3/packed x4) issued before use -> high MLP. s2 in LDS.
//     atomicExch scatter (16B writeback granularity vs 64B line).
// ---------------------------------------------------------------------------
__global__ __launch_bounds__(256) void k_att_place(
    const int* __restrict__ src, const int* __restrict__ dst,
    const int* __restrict__ etype,
    const float* __restrict__ s1, const float* __restrict__ s2,
    const float* __restrict__ s3,
    const int* __restrict__ packed, const int* __restrict__ bpre,
    const int* __restrict__ eord,
    unsigned long long* __restrict__ rec, int n_edges)
{
    __shared__ float s2l[64];
    if (threadIdx.x < 64) s2l[threadIdx.x] = s2[threadIdx.x];
    __syncthreads();

    int e = (blockIdx.x * 256 + threadIdx.x) * 4;
    if (e >= n_edges) return;

    if (e + 3 < n_edges) {
        int4 sv = *reinterpret_cast<const int4*>(&src[e]);
        int4 dv = *reinterpret_cast<const int4*>(&dst[e]);
        int4 tv = *reinterpret_cast<const int4*>(&etype[e]);
        int4 ov = *reinterpret_cast<const int4*>(&eord[e]);
        int sa[4] = {sv.x, sv.y, sv.z, sv.w};
        int da[4] = {dv.x, dv.y, dv.z, dv.w};
        int ta[4] = {tv.x, tv.y, tv.z, tv.w};
        int oa[4] = {ov.x, ov.y, ov.z, ov.w};
        float s1v[4], s3v[4];
        int pk[4], bp[4];
        #pragma unroll
        for (int j = 0; j < 4; ++j) {
            s1v[j] = s1[sa[j]];
            s3v[j] = s3[da[j]];
            pk[j]  = packed[da[j]];
            bp[j]  = bpre[da[j] >> 10];
        }
        #pragma unroll
        for (int j = 0; j < 4; ++j) {
            float v = s1v[j] + s2l[ta[j]] + s3v[j];
            v = (v >= 0.f) ? v : 0.2f * v;
            const float w = __expf(v);
            const int pos = (int)(((unsigned)pk[j]) >> 12) + bp[j] + oa[j];
            unsigned long long r =
                ((unsigned long long)__float_as_uint(w) << 32) |
                (unsigned)(sa[j] << 8);
            atomicExch(&rec[pos], r);
        }
    } else {
        for (int k = 0; k < 4 && e + k < n_edges; ++k) {
            const int s = src[e + k], d = dst[e + k];
            float v = s1[s] + s2l[etype[e + k]] + s3[d];
            v = (v >= 0.f) ? v : 0.2f * v;
            const float w = __expf(v);
            const int pos = (int)(((unsigned)packed[d]) >> 12) + bpre[d >> 10] + eord[e + k];
            unsigned long long r =
                ((unsigned long long)__float_as_uint(w) << 32) |
                (unsigned)(s << 8);
            atomicExch(&rec[pos], r);
        }
    }
}

// ---------------------------------------------------------------------------
// K6: gather-reduce. One wave per node split into 4x16-lane quarters; each
//     quarter owns a contiguous chunk of the edge list, lane owns 8 cols
//     (dwordx4/row). Batch-4 -> up to 16 independent row gathers in flight.
// ---------------------------------------------------------------------------
__global__ __launch_bounds__(256) void k_gather(
    const char* __restrict__ xtb, const unsigned long long* __restrict__ rec,
    const int* __restrict__ packed, const int* __restrict__ bpre,
    float* __restrict__ out, int n_nodes)
{
    const int n = blockIdx.x * 4 + (threadIdx.x >> 6);
    if (n >= n_nodes) return;
    const int lane = threadIdx.x & 63;
    const int l15  = lane & 15;
    const int q    = lane >> 4;
    const unsigned pd = (unsigned)packed[n];
    const int start = __builtin_amdgcn_readfirstlane((int)(pd >> 12) + bpre[n >> 10]);
    const int cnt   = __builtin_amdgcn_readfirstlane((int)(pd & 0xFFFu));
    const int cq    = (cnt + 3) >> 2;            // chunk size per quarter
    const int qm    = min(cq, cnt - q * cq);     // valid entries in this quarter
    const unsigned laneoff = (unsigned)l15 * 16u;

    float acc[8] = {0.f, 0.f, 0.f, 0.f, 0.f, 0.f, 0.f, 0.f};
    float wsum = 0.f;

    for (int k0 = 0; k0 < cq; k0 += 4) {
        unsigned off[4];
        float w[4];
        #pragma unroll
        for (int j = 0; j < 4; ++j) {
            int li  = q * cq + k0 + j;
            int idx = start + min(li, cnt - 1);  // cnt>=1 whenever loop runs
            unsigned long long rr = __builtin_nontemporal_load(&rec[idx]);
            off[j] = (unsigned)rr;               // src byte offset
            w[j] = ((k0 + j) < qm) ? __uint_as_float((unsigned)(rr >> 32)) : 0.f;
        }
        uint4 p[4];
        #pragma unroll
        for (int j = 0; j < 4; ++j)
            p[j] = *reinterpret_cast<const uint4*>(xtb + (size_t)(off[j] + laneoff));
        #pragma unroll
        for (int j = 0; j < 4; ++j) {
            wsum += w[j];
            acc[0] = fmaf(w[j], bf_lo(p[j].x), acc[0]);
            acc[1] = fmaf(w[j], bf_hi(p[j].x), acc[1]);
            acc[2] = fmaf(w[j], bf_lo(p[j].y), acc[2]);
            acc[3] = fmaf(w[j], bf_hi(p[j].y), acc[3]);
            acc[4] = fmaf(w[j], bf_lo(p[j].z), acc[4]);
            acc[5] = fmaf(w[j], bf_hi(p[j].z), acc[5]);
            acc[6] = fmaf(w[j], bf_lo(p[j].w), acc[6]);
            acc[7] = fmaf(w[j], bf_hi(p[j].w), acc[7]);
        }
    }

    #pragma unroll
    for (int j = 0; j < 8; ++j) {
        acc[j] += __shfl_xor(acc[j], 16);
        acc[j] += __shfl_xor(acc[j], 32);
    }
    wsum += __shfl_xor(wsum, 16);
    wsum += __shfl_xor(wsum, 32);

    if (q == 0) {
        const float inv = 1.0f / (wsum + 1e-10f);
        f32x4 o0 = {acc[0] * inv, acc[1] * inv, acc[2] * inv, acc[3] * inv};
        f32x4 o1 = {acc[4] * inv, acc[5] * inv, acc[6] * inv, acc[7] * inv};
        f32x4* po = reinterpret_cast<f32x4*>(out + (size_t)n * NDIM + l15 * 8);
        __builtin_nontemporal_store(o0, po);
        __builtin_nontemporal_store(o1, po + 1);
    }
}

extern "C" void kernel_launch(void* const* d_in, const int* in_sizes, int n_in,
                              void* d_out, int out_size, void* d_ws, size_t ws_size,
                              hipStream_t stream)
{
    const float* x    = (const float*)d_in[0];
    const int*   ei   = (const int*)d_in[1];   // [2,E]: src row then dst row
    const int*   et   = (const int*)d_in[2];
    const float* W    = (const float*)d_in[3];
    const float* W_r  = (const float*)d_in[4];
    const float* a    = (const float*)d_in[5];
    const float* rel  = (const float*)d_in[6];
    float* out = (float*)d_out;

    const int E  = in_sizes[2];
    const int N  = in_sizes[0] / NDIM;
    const int NB = (N + 1023) / 1024;           // 98 (<=128 req'd by k_scan2)

    char* p = (char*)d_ws;
    auto take = [&](size_t bytes) {
        char* q = p;
        p += (bytes + 15) & ~(size_t)15;
        return q;
    };
    unsigned* xtb        = (unsigned*)take((size_t)N * 64 * 4);   // bf16x2
    unsigned short* Wt   = (unsigned short*)take(NDIM * NDIM * 2);
    float* s1            = (float*)take((size_t)N * 4);
    float* s3            = (float*)take((size_t)N * 4);
    float* s2            = (float*)take(64 * 4);
    int* deg             = (int*)take((size_t)N * 4);
    int* packed          = (int*)take((size_t)N * 4);             // {prefix:20,deg:12}
    int* btot            = (int*)take(128 * 4);
    int* eord            = (int*)take((size_t)E * 4);
    unsigned long long* rec = (unsigned long long*)take((size_t)E * 8);

    const int* srcArr = ei;
    const int* dstArr = ei + E;

    (void)hipMemsetAsync(deg, 0, (size_t)N * sizeof(int), stream);

    k_prep<<<2, 256, 0, stream>>>(W, W_r, a, rel, Wt, s2);
    k_xt<<<(N + 127) / 128, 256, 0, stream>>>(x, Wt, a, xtb, s1, s3, N);
    k_count<<<(E + 1023) / 1024, 256, 0, stream>>>(dstArr, deg, eord, E);
    k_scan1<<<NB, 1024, 0, stream>>>(deg, packed, btot, N);
    k_scan2<<<1, 128, 0, stream>>>(btot, NB);
    k_att_place<<<(E + 1023) / 1024, 256, 0, stream>>>(
        srcArr, dstArr, et, s1, s2, s3, packed, btot, eord, rec, E);
    k_gather<<<(N + 3) / 4, 256, 0, stream>>>(
        (const char*)xtb, rec, packed, btot, out, N);
}